// Round 1
// baseline (433.947 us; speedup 1.0000x reference)
//
#include <hip/hip_runtime.h>
#include <hip/hip_bf16.h>

#define QN 4096
#define CN 4096
#define DN 1024
#define EPSV 1e-6f

#define BM 128
#define BN 128
#define LDSP 40   // padded LDS row length (bf16 elems): 80B rows -> 2-way bank aliasing (free), 16B aligned

#define MATSZ ((size_t)QN * DN)

using s16x8  = __attribute__((ext_vector_type(8))) short;
using bf16x8 = __attribute__((ext_vector_type(8))) __bf16;
using f32x4  = __attribute__((ext_vector_type(4))) float;

static __device__ __forceinline__ unsigned short f2bf_rne(float x) {
  unsigned int u = __float_as_uint(x);
  unsigned int r = (u + 0x7FFFu + ((u >> 16) & 1u)) >> 16;
  return (unsigned short)r;
}
static __device__ __forceinline__ float bf2f(unsigned short h) {
  return __uint_as_float(((unsigned int)h) << 16);
}

// ws16 layout (ushort elements):
//  0*MATSZ t_hi_rgb | 1 t_lo_rgb | 2 t_hi_flow | 3 t_lo_flow
//  4 c_hi_rgb | 5 c_lo_rgb | 6 c_hi_flow | 7 c_lo_flow
// then norms (float): tn_r[QN], tn_f[QN], cn_r[CN], cn_f[CN]

__global__ void prep_kernel(const float* __restrict__ tgt_r, const float* __restrict__ tgt_f,
                            const float* __restrict__ ctx_r, const float* __restrict__ ctx_f,
                            unsigned short* __restrict__ ws16, float* __restrict__ norms) {
  const int row = blockIdx.x;
  const int mat = blockIdx.y;
  const int t = threadIdx.x;
  const float* src; unsigned short* hi; unsigned short* lo; float* nrm; float eps;
  switch (mat) {
    case 0:  src = tgt_r; hi = ws16 + 0*MATSZ; lo = ws16 + 1*MATSZ; nrm = norms + 0*QN; eps = EPSV; break;
    case 1:  src = tgt_f; hi = ws16 + 2*MATSZ; lo = ws16 + 3*MATSZ; nrm = norms + 1*QN; eps = EPSV; break;
    case 2:  src = ctx_r; hi = ws16 + 4*MATSZ; lo = ws16 + 5*MATSZ; nrm = norms + 2*QN; eps = 0.f;  break;
    default: src = ctx_f; hi = ws16 + 6*MATSZ; lo = ws16 + 7*MATSZ; nrm = norms + 3*QN; eps = 0.f;  break;
  }
  const size_t base = (size_t)row * DN;
  float4 v = ((const float4*)(src + base))[t];
  float a[4] = {v.x + eps, v.y + eps, v.z + eps, v.w + eps};
  float ss = 0.f;
  unsigned short hh[4], ll[4];
#pragma unroll
  for (int k = 0; k < 4; ++k) {
    ss += a[k] * a[k];
    hh[k] = f2bf_rne(a[k]);
    ll[k] = f2bf_rne(a[k] - bf2f(hh[k]));
  }
  ((ushort4*)(hi + base))[t] = make_ushort4(hh[0], hh[1], hh[2], hh[3]);
  ((ushort4*)(lo + base))[t] = make_ushort4(ll[0], ll[1], ll[2], ll[3]);

#pragma unroll
  for (int o = 32; o > 0; o >>= 1) ss += __shfl_down(ss, o);
  __shared__ float red[4];
  if ((t & 63) == 0) red[t >> 6] = ss;
  __syncthreads();
  if (t == 0) nrm[row] = red[0] + red[1] + red[2] + red[3];
}

// Dual bf16x3 GEMM + distance/exp epilogue. One block = 128x128 output tile,
// 4 waves in 2x2, each wave 64x64 via 4x4 frags of mfma_f32_16x16x32_bf16.
__global__ __launch_bounds__(256, 2)
void gemm_kernel(const unsigned short* __restrict__ ws16,
                 const float* __restrict__ norms,
                 const float* __restrict__ c_r, const float* __restrict__ c_f,
                 float* __restrict__ out) {
  __shared__ unsigned short As[BM * LDSP];
  __shared__ unsigned short Bs[BN * LDSP];

  const int t = threadIdx.x;
  const int lane = t & 63;
  const int wid = t >> 6;
  const int wr = wid >> 1;
  const int wc = wid & 1;
  const int row0 = blockIdx.y * BM;   // target rows
  const int col0 = blockIdx.x * BN;   // context cols

  const unsigned short* TH[2] = { ws16 + 0*MATSZ, ws16 + 2*MATSZ };
  const unsigned short* TL[2] = { ws16 + 1*MATSZ, ws16 + 3*MATSZ };
  const unsigned short* CH[2] = { ws16 + 4*MATSZ, ws16 + 6*MATSZ };
  const unsigned short* CL[2] = { ws16 + 5*MATSZ, ws16 + 7*MATSZ };

  f32x4 acc[2][4][4];
#pragma unroll
  for (int m = 0; m < 2; ++m)
#pragma unroll
    for (int i = 0; i < 4; ++i)
#pragma unroll
      for (int j = 0; j < 4; ++j)
        acc[m][i][j] = (f32x4){0.f, 0.f, 0.f, 0.f};

  const int srow = t >> 1;          // staged tile row 0..127
  const int scol = (t & 1) * 16;    // staged col chunk 0/16
  const int lr = lane & 15;         // frag row-in-16
  const int lq = lane >> 4;         // quad 0..3

  const int aw = srow * LDSP + scol;
  int ard[4], brd[4];
#pragma unroll
  for (int i = 0; i < 4; ++i) {
    ard[i] = (wr * 64 + i * 16 + lr) * LDSP + lq * 8;
    brd[i] = (wc * 64 + i * 16 + lr) * LDSP + lq * 8;
  }

#pragma unroll
  for (int mod = 0; mod < 2; ++mod) {
    const unsigned short* aterm[3] = { TH[mod], TH[mod], TL[mod] };
    const unsigned short* bterm[3] = { CH[mod], CL[mod], CH[mod] };
#pragma unroll
    for (int term = 0; term < 3; ++term) {
      const unsigned short* Ab = aterm[term] + (size_t)(row0 + srow) * DN + scol;
      const unsigned short* Bb = bterm[term] + (size_t)(col0 + srow) * DN + scol;
      for (int kc = 0; kc < DN / 32; ++kc) {
        const int k0 = kc * 32;
        // global -> regs (issued early, before barrier)
        s16x8 va0 = *(const s16x8*)(Ab + k0);
        s16x8 va1 = *(const s16x8*)(Ab + k0 + 8);
        s16x8 vb0 = *(const s16x8*)(Bb + k0);
        s16x8 vb1 = *(const s16x8*)(Bb + k0 + 8);
        __syncthreads();   // previous tile fully consumed
        *(s16x8*)(As + aw)     = va0;
        *(s16x8*)(As + aw + 8) = va1;
        *(s16x8*)(Bs + aw)     = vb0;
        *(s16x8*)(Bs + aw + 8) = vb1;
        __syncthreads();
        bf16x8 af[4], bfr[4];
#pragma unroll
        for (int i = 0; i < 4; ++i) af[i]  = *(const bf16x8*)(As + ard[i]);
#pragma unroll
        for (int j = 0; j < 4; ++j) bfr[j] = *(const bf16x8*)(Bs + brd[j]);
#pragma unroll
        for (int i = 0; i < 4; ++i)
#pragma unroll
          for (int j = 0; j < 4; ++j)
            acc[mod][i][j] = __builtin_amdgcn_mfma_f32_16x16x32_bf16(af[i], bfr[j], acc[mod][i][j], 0, 0, 0);
      }
    }
  }

  // epilogue: sq = ||t||^2 + ||c||^2 - 2*dot ; p = w_r*exp(-d_r) + w_f*exp(-d_f)
  const float* tn_r = norms;
  const float* tn_f = norms + QN;
  const float* cn_r = norms + 2 * QN;
  const float* cn_f = norms + 3 * QN;

#pragma unroll
  for (int i = 0; i < 4; ++i) {
#pragma unroll
    for (int r = 0; r < 4; ++r) {
      const int tq = row0 + wr * 64 + i * 16 + lq * 4 + r;   // C/D row = (lane>>4)*4 + reg
      const float tnr = tn_r[tq];
      const float tnf = tn_f[tq];
      const float cr = c_r[tq], cf = c_f[tq];
      const float inv = 1.f / (cr + cf);
      const float wgr = cr * inv, wgf = cf * inv;
#pragma unroll
      for (int j = 0; j < 4; ++j) {
        const int cc = col0 + wc * 64 + j * 16 + lr;          // C/D col = lane&15
        const float sr = tnr + cn_r[cc] - 2.f * acc[0][i][j][r];
        const float sf = tnf + cn_f[cc] - 2.f * acc[1][i][j][r];
        const float dr = sqrtf(fmaxf(sr, 0.f));
        const float df = sqrtf(fmaxf(sf, 0.f));
        const float p = wgr * __expf(-dr) + wgf * __expf(-df);
        out[(size_t)tq * CN + cc] = p;
      }
    }
  }
}

// Per-row sum + normalize, in place. Deterministic (no atomics).
__global__ void norm_kernel(float* __restrict__ out) {
  const int row = blockIdx.x;
  const int t = threadIdx.x;
  float4* p = (float4*)(out + (size_t)row * CN);
  float4 v[4];
  float s = 0.f;
#pragma unroll
  for (int i = 0; i < 4; ++i) {
    v[i] = p[t + 256 * i];
    s += v[i].x + v[i].y + v[i].z + v[i].w;
  }
#pragma unroll
  for (int o = 32; o > 0; o >>= 1) s += __shfl_down(s, o);
  __shared__ float red[4];
  if ((t & 63) == 0) red[t >> 6] = s;
  __syncthreads();
  const float inv = 1.f / (red[0] + red[1] + red[2] + red[3]);
#pragma unroll
  for (int i = 0; i < 4; ++i) {
    v[i].x *= inv; v[i].y *= inv; v[i].z *= inv; v[i].w *= inv;
    p[t + 256 * i] = v[i];
  }
}

extern "C" void kernel_launch(void* const* d_in, const int* in_sizes, int n_in,
                              void* d_out, int out_size, void* d_ws, size_t ws_size,
                              hipStream_t stream) {
  const float* ctx_r = (const float*)d_in[0];
  const float* ctx_f = (const float*)d_in[1];
  const float* tgt_r = (const float*)d_in[2];
  const float* tgt_f = (const float*)d_in[3];
  const float* c_r   = (const float*)d_in[4];
  const float* c_f   = (const float*)d_in[5];
  float* out = (float*)d_out;
  unsigned short* ws16 = (unsigned short*)d_ws;
  float* norms = (float*)(ws16 + 8 * MATSZ);

  prep_kernel<<<dim3(QN, 4), 256, 0, stream>>>(tgt_r, tgt_f, ctx_r, ctx_f, ws16, norms);
  gemm_kernel<<<dim3(CN / BN, QN / BM), 256, 0, stream>>>(ws16, norms, c_r, c_f, out);
  norm_kernel<<<QN, 256, 0, stream>>>(out);
}

// Round 2
// 340.125 us; speedup vs baseline: 1.2758x; 1.2758x over previous
//
#include <hip/hip_runtime.h>
#include <hip/hip_bf16.h>

#define QN 4096
#define CN 4096
#define DN 1024
#define EPSV 1e-6f

#define BM 128
#define BN 128
#define BK 32
#define TILE (BM * BK)          // 4096 bf16 elems = 8 KB per staged tile

#define MATSZ ((size_t)QN * DN)

using bf16x8 = __attribute__((ext_vector_type(8))) __bf16;
using f32x4  = __attribute__((ext_vector_type(4))) float;

static __device__ __forceinline__ unsigned short f2bf_rne(float x) {
  unsigned int u = __float_as_uint(x);
  unsigned int r = (u + 0x7FFFu + ((u >> 16) & 1u)) >> 16;
  return (unsigned short)r;
}
static __device__ __forceinline__ float bf2f(unsigned short h) {
  return __uint_as_float(((unsigned int)h) << 16);
}

// async global->LDS, 16B per lane; LDS dest is wave-uniform base + lane*16
static __device__ __forceinline__ void gload_lds16(const unsigned short* g, unsigned short* l) {
  __builtin_amdgcn_global_load_lds(
      (const __attribute__((address_space(1))) unsigned int*)g,
      (__attribute__((address_space(3))) unsigned int*)l, 16, 0, 0);
}

// ws16 layout (ushort elements):
//  0*MATSZ t_hi_rgb | 1 t_lo_rgb | 2 t_hi_flow | 3 t_lo_flow
//  4 c_hi_rgb | 5 c_lo_rgb | 6 c_hi_flow | 7 c_lo_flow
// then norms (float): tn_r[QN], tn_f[QN], cn_r[CN], cn_f[CN]

__global__ void prep_kernel(const float* __restrict__ tgt_r, const float* __restrict__ tgt_f,
                            const float* __restrict__ ctx_r, const float* __restrict__ ctx_f,
                            unsigned short* __restrict__ ws16, float* __restrict__ norms) {
  const int row = blockIdx.x;
  const int mat = blockIdx.y;
  const int t = threadIdx.x;
  const float* src; unsigned short* hi; unsigned short* lo; float* nrm; float eps;
  switch (mat) {
    case 0:  src = tgt_r; hi = ws16 + 0*MATSZ; lo = ws16 + 1*MATSZ; nrm = norms + 0*QN; eps = EPSV; break;
    case 1:  src = tgt_f; hi = ws16 + 2*MATSZ; lo = ws16 + 3*MATSZ; nrm = norms + 1*QN; eps = EPSV; break;
    case 2:  src = ctx_r; hi = ws16 + 4*MATSZ; lo = ws16 + 5*MATSZ; nrm = norms + 2*QN; eps = 0.f;  break;
    default: src = ctx_f; hi = ws16 + 6*MATSZ; lo = ws16 + 7*MATSZ; nrm = norms + 3*QN; eps = 0.f;  break;
  }
  const size_t base = (size_t)row * DN;
  float4 v = ((const float4*)(src + base))[t];
  float a[4] = {v.x + eps, v.y + eps, v.z + eps, v.w + eps};
  float ss = 0.f;
  unsigned short hh[4], ll[4];
#pragma unroll
  for (int k = 0; k < 4; ++k) {
    ss += a[k] * a[k];
    hh[k] = f2bf_rne(a[k]);
    ll[k] = f2bf_rne(a[k] - bf2f(hh[k]));
  }
  ((ushort4*)(hi + base))[t] = make_ushort4(hh[0], hh[1], hh[2], hh[3]);
  ((ushort4*)(lo + base))[t] = make_ushort4(ll[0], ll[1], ll[2], ll[3]);

#pragma unroll
  for (int o = 32; o > 0; o >>= 1) ss += __shfl_down(ss, o);
  __shared__ float red[4];
  if ((t & 63) == 0) red[t >> 6] = ss;
  __syncthreads();
  if (t == 0) nrm[row] = red[0] + red[1] + red[2] + red[3];
}

// Dual bf16x3 GEMM + distance/exp epilogue.
// One block = 128x128 tile, 4 waves 2x2, each wave 64x64 via 4x4 frags of
// mfma_f32_16x16x32_bf16. Per K-chunk: stage Ah/Al/Bh/Bl via global_load_lds
// (8 wave-instrs), then 48 MFMAs (3 split-terms fused in one sweep).
__global__ __launch_bounds__(256, 2)
void gemm_kernel(const unsigned short* __restrict__ ws16,
                 const float* __restrict__ norms,
                 const float* __restrict__ c_r, const float* __restrict__ c_f,
                 float* __restrict__ out) {
  __shared__ unsigned short S[4 * TILE];   // Ah | Al | Bh | Bl, each 128x32 row-major, unpadded

  const int t = threadIdx.x;
  const int lane = t & 63;
  const int wid = t >> 6;
  const int wr = wid >> 1;
  const int wc = wid & 1;
  const int row0 = blockIdx.y * BM;   // target rows
  const int col0 = blockIdx.x * BN;   // context cols

  f32x4 acc[2][4][4];
#pragma unroll
  for (int m = 0; m < 2; ++m)
#pragma unroll
    for (int i = 0; i < 4; ++i)
#pragma unroll
      for (int j = 0; j < 4; ++j)
        acc[m][i][j] = (f32x4){0.f, 0.f, 0.f, 0.f};

  // staging geometry: wave w stages rows [w*16, w*16+16) of each 64-row half;
  // lane covers row w*16 + lane/4, bf16 cols (lane%4)*8 .. +8  (16 B)
  const int sr = wid * 16 + (lane >> 2);   // 0..63
  const int sc = (lane & 3) * 8;
  const size_t aoff = (size_t)(row0 + sr) * DN + sc;
  const size_t boff = (size_t)(col0 + sr) * DN + sc;
  const size_t ghalf = (size_t)64 * DN;    // +64 rows in global
  const int lhalf = 64 * BK;               // +64 rows in LDS tile
  unsigned short* ldsW = S + (size_t)wid * 16 * BK;  // wave-uniform base (lane*16B implicit)

  // fragment read offsets (bf16 elems, row stride BK=32)
  const int lr = lane & 15;
  const int lq = lane >> 4;
  int ra[4], rb[4];
#pragma unroll
  for (int i = 0; i < 4; ++i) {
    ra[i] = (wr * 64 + i * 16 + lr) * BK + lq * 8;
    rb[i] = (wc * 64 + i * 16 + lr) * BK + lq * 8;
  }

#pragma unroll
  for (int mod = 0; mod < 2; ++mod) {
    const unsigned short* pAh = ws16 + (size_t)(mod ? 2 : 0) * MATSZ + aoff;
    const unsigned short* pAl = ws16 + (size_t)(mod ? 3 : 1) * MATSZ + aoff;
    const unsigned short* pBh = ws16 + (size_t)(mod ? 6 : 4) * MATSZ + boff;
    const unsigned short* pBl = ws16 + (size_t)(mod ? 7 : 5) * MATSZ + boff;
    for (int kc = 0; kc < DN / BK; ++kc) {
      const int k = kc * BK;
      __syncthreads();   // previous chunk fully consumed
      gload_lds16(pAh + k,         ldsW + 0 * TILE);
      gload_lds16(pAh + k + ghalf, ldsW + 0 * TILE + lhalf);
      gload_lds16(pAl + k,         ldsW + 1 * TILE);
      gload_lds16(pAl + k + ghalf, ldsW + 1 * TILE + lhalf);
      gload_lds16(pBh + k,         ldsW + 2 * TILE);
      gload_lds16(pBh + k + ghalf, ldsW + 2 * TILE + lhalf);
      gload_lds16(pBl + k,         ldsW + 3 * TILE);
      gload_lds16(pBl + k + ghalf, ldsW + 3 * TILE + lhalf);
      __syncthreads();   // vmcnt drained -> LDS valid

      bf16x8 ah[4], al[4], bh[4], bl[4];
#pragma unroll
      for (int i = 0; i < 4; ++i) {
        ah[i] = *(const bf16x8*)(S + 0 * TILE + ra[i]);
        al[i] = *(const bf16x8*)(S + 1 * TILE + ra[i]);
      }
#pragma unroll
      for (int j = 0; j < 4; ++j) {
        bh[j] = *(const bf16x8*)(S + 2 * TILE + rb[j]);
        bl[j] = *(const bf16x8*)(S + 3 * TILE + rb[j]);
      }
#pragma unroll
      for (int i = 0; i < 4; ++i)
#pragma unroll
        for (int j = 0; j < 4; ++j) {
          acc[mod][i][j] = __builtin_amdgcn_mfma_f32_16x16x32_bf16(ah[i], bh[j], acc[mod][i][j], 0, 0, 0);
          acc[mod][i][j] = __builtin_amdgcn_mfma_f32_16x16x32_bf16(ah[i], bl[j], acc[mod][i][j], 0, 0, 0);
          acc[mod][i][j] = __builtin_amdgcn_mfma_f32_16x16x32_bf16(al[i], bh[j], acc[mod][i][j], 0, 0, 0);
        }
    }
  }

  // epilogue: sq = ||t||^2 + ||c||^2 - 2*dot ; p = w_r*exp(-d_r) + w_f*exp(-d_f)
  const float* tn_r = norms;
  const float* tn_f = norms + QN;
  const float* cn_r = norms + 2 * QN;
  const float* cn_f = norms + 3 * QN;

#pragma unroll
  for (int i = 0; i < 4; ++i) {
#pragma unroll
    for (int r = 0; r < 4; ++r) {
      const int tq = row0 + wr * 64 + i * 16 + lq * 4 + r;   // C/D row = (lane>>4)*4 + reg
      const float tnr = tn_r[tq];
      const float tnf = tn_f[tq];
      const float cr = c_r[tq], cf = c_f[tq];
      const float inv = 1.f / (cr + cf);
      const float wgr = cr * inv, wgf = cf * inv;
#pragma unroll
      for (int j = 0; j < 4; ++j) {
        const int cc = col0 + wc * 64 + j * 16 + lr;          // C/D col = lane&15
        const float sr_ = tnr + cn_r[cc] - 2.f * acc[0][i][j][r];
        const float sf_ = tnf + cn_f[cc] - 2.f * acc[1][i][j][r];
        const float dr = sqrtf(fmaxf(sr_, 0.f));
        const float df = sqrtf(fmaxf(sf_, 0.f));
        const float p = wgr * __expf(-dr) + wgf * __expf(-df);
        out[(size_t)tq * CN + cc] = p;
      }
    }
  }
}

// Per-row sum + normalize, in place. Deterministic (no atomics).
__global__ void norm_kernel(float* __restrict__ out) {
  const int row = blockIdx.x;
  const int t = threadIdx.x;
  float4* p = (float4*)(out + (size_t)row * CN);
  float4 v[4];
  float s = 0.f;
#pragma unroll
  for (int i = 0; i < 4; ++i) {
    v[i] = p[t + 256 * i];
    s += v[i].x + v[i].y + v[i].z + v[i].w;
  }
#pragma unroll
  for (int o = 32; o > 0; o >>= 1) s += __shfl_down(s, o);
  __shared__ float red[4];
  if ((t & 63) == 0) red[t >> 6] = s;
  __syncthreads();
  const float inv = 1.f / (red[0] + red[1] + red[2] + red[3]);
#pragma unroll
  for (int i = 0; i < 4; ++i) {
    v[i].x *= inv; v[i].y *= inv; v[i].z *= inv; v[i].w *= inv;
    p[t + 256 * i] = v[i];
  }
}

extern "C" void kernel_launch(void* const* d_in, const int* in_sizes, int n_in,
                              void* d_out, int out_size, void* d_ws, size_t ws_size,
                              hipStream_t stream) {
  const float* ctx_r = (const float*)d_in[0];
  const float* ctx_f = (const float*)d_in[1];
  const float* tgt_r = (const float*)d_in[2];
  const float* tgt_f = (const float*)d_in[3];
  const float* c_r   = (const float*)d_in[4];
  const float* c_f   = (const float*)d_in[5];
  float* out = (float*)d_out;
  unsigned short* ws16 = (unsigned short*)d_ws;
  float* norms = (float*)(ws16 + 8 * MATSZ);

  prep_kernel<<<dim3(QN, 4), 256, 0, stream>>>(tgt_r, tgt_f, ctx_r, ctx_f, ws16, norms);
  gemm_kernel<<<dim3(CN / BN, QN / BM), 256, 0, stream>>>(ws16, norms, c_r, c_f, out);
  norm_kernel<<<QN, 256, 0, stream>>>(out);
}

// Round 3
// 218.351 us; speedup vs baseline: 1.9874x; 1.5577x over previous
//
#include <hip/hip_runtime.h>
#include <hip/hip_bf16.h>

#define QN 4096
#define CN 4096
#define DN 1024
#define EPSV 1e-6f

#define BM 128
#define BN 128
#define BK 64
#define TILE (BM * BK)          // 8192 bf16 elems = 16 KB per staged tile

#define MATSZ ((size_t)QN * DN)

using bf16x8 = __attribute__((ext_vector_type(8))) __bf16;
using f32x4  = __attribute__((ext_vector_type(4))) float;

static __device__ __forceinline__ unsigned short f2bf_rne(float x) {
  unsigned int u = __float_as_uint(x);
  unsigned int r = (u + 0x7FFFu + ((u >> 16) & 1u)) >> 16;
  return (unsigned short)r;
}
static __device__ __forceinline__ float bf2f(unsigned short h) {
  return __uint_as_float(((unsigned int)h) << 16);
}

// async global->LDS, 16B per lane; LDS dest is wave-uniform base + lane*16
static __device__ __forceinline__ void gload_lds16(const unsigned short* g, unsigned short* l) {
  __builtin_amdgcn_global_load_lds(
      (const __attribute__((address_space(1))) unsigned int*)g,
      (__attribute__((address_space(3))) unsigned int*)l, 16, 0, 0);
}

// ws16 layout (ushort elems): 0:t_rgb | 1:t_flow | 2:c_rgb | 3:c_flow (bf16-rounded)
// then norms (float): tn_r[QN], tn_f[QN], cn_r[CN], cn_f[CN]
// Norms are computed from the ROUNDED values so sq = ||a~||^2+||b~||^2-2 a~.b~
// is the exact squared distance of the perturbed vectors (error = rounding
// perturbation only, ~1e-3 relative on exp(-d) vs an 8-ulp bf16 budget).

__global__ void prep_kernel(const float* __restrict__ tgt_r, const float* __restrict__ tgt_f,
                            const float* __restrict__ ctx_r, const float* __restrict__ ctx_f,
                            unsigned short* __restrict__ ws16, float* __restrict__ norms) {
  const int row = blockIdx.x;
  const int mat = blockIdx.y;
  const int t = threadIdx.x;
  const float* src; float eps;
  switch (mat) {
    case 0:  src = tgt_r; eps = EPSV; break;
    case 1:  src = tgt_f; eps = EPSV; break;
    case 2:  src = ctx_r; eps = 0.f;  break;
    default: src = ctx_f; eps = 0.f;  break;
  }
  unsigned short* hi = ws16 + (size_t)mat * MATSZ;
  float* nrm = norms + (size_t)mat * QN;
  const size_t base = (size_t)row * DN;
  float4 v = ((const float4*)(src + base))[t];
  float a[4] = {v.x + eps, v.y + eps, v.z + eps, v.w + eps};
  float ss = 0.f;
  unsigned short hh[4];
#pragma unroll
  for (int k = 0; k < 4; ++k) {
    hh[k] = f2bf_rne(a[k]);
    float f = bf2f(hh[k]);         // norm of the rounded value (consistency)
    ss += f * f;
  }
  ((ushort4*)(hi + base))[t] = make_ushort4(hh[0], hh[1], hh[2], hh[3]);

#pragma unroll
  for (int o = 32; o > 0; o >>= 1) ss += __shfl_down(ss, o);
  __shared__ float red[4];
  if ((t & 63) == 0) red[t >> 6] = ss;
  __syncthreads();
  if (t == 0) nrm[row] = red[0] + red[1] + red[2] + red[3];
}

// Dual (rgb+flow) single-term bf16 GEMM + distance/exp epilogue.
// Block = 128x128 tile, 4 waves 2x2, wave = 64x64 via 4x4 frags of
// mfma_f32_16x16x32_bf16. BK=64: per barrier-pair stage 4 tiles (A_r,A_f,
// B_r,B_f; 16 global_load_lds) then 64 MFMAs in 2 K-subchunks.
// LDS 16B-chunks are XOR-swizzled by (row&7) on the *source* address to
// break the all-rows-same-bank-phase of the 128 B row stride.
__global__ __launch_bounds__(256, 2)
void gemm_kernel(const unsigned short* __restrict__ ws16,
                 const float* __restrict__ norms,
                 const float* __restrict__ c_r, const float* __restrict__ c_f,
                 float* __restrict__ out) {
  __shared__ unsigned short S[4 * TILE];   // Ar | Af | Br | Bf, each 128x64, swizzled

  const int t = threadIdx.x;
  const int lane = t & 63;
  const int wid = t >> 6;
  const int wr = wid >> 1;
  const int wc = wid & 1;
  const int row0 = blockIdx.y * BM;   // target rows
  const int col0 = blockIdx.x * BN;   // context cols

  f32x4 acc[2][4][4];
#pragma unroll
  for (int m = 0; m < 2; ++m)
#pragma unroll
    for (int i = 0; i < 4; ++i)
#pragma unroll
      for (int j = 0; j < 4; ++j)
        acc[m][i][j] = (f32x4){0.f, 0.f, 0.f, 0.f};

  // staging: per call site the block covers 32 rows x 64 cols (4 KB).
  // wave w, lane l -> LDS row w*8 + (l>>3), LDS chunk (l&7) (chunk = 8 bf16).
  // source global chunk = (l&7) ^ (l>>3)   [row&7 == l>>3 since w*8, it*32 are mult of 8]
  const int srw = lane >> 3;               // 0..7
  const int sch = (lane & 7) ^ srw;        // swizzled source chunk
  const size_t src_off = (size_t)(wid * 8 + srw) * DN + sch * 8;
  const size_t aoff = (size_t)row0 * DN + src_off;
  const size_t boff = (size_t)col0 * DN + src_off;
  unsigned short* ldsW = S + wid * 8 * BK; // + it*32*BK per call, lane*16B implicit

  const unsigned short* pAr = ws16 + 0 * MATSZ + aoff;
  const unsigned short* pAf = ws16 + 1 * MATSZ + aoff;
  const unsigned short* pBr = ws16 + 2 * MATSZ + boff;
  const unsigned short* pBf = ws16 + 3 * MATSZ + boff;

  // fragment read offsets (bf16 elems, row stride BK=64), XOR-unswizzle:
  // row R = (wr|wc)*64 + i*16 + lr  ->  R&7 == lr&7 ; chunk c = lq + 4*ksub
  const int lr = lane & 15;
  const int lq = lane >> 4;
  const int sc0 = (lq ^ (lr & 7)) * 8;     // ksub=0 chunk offset (elems)
  int ra[4], rb[4];
#pragma unroll
  for (int i = 0; i < 4; ++i) {
    ra[i] = (wr * 64 + i * 16 + lr) * BK + sc0;
    rb[i] = (wc * 64 + i * 16 + lr) * BK + sc0;
  }
  // ksub=1: chunk = (lq+4)^(lr&7) = sc0/8 ^ 4  ->  offset ^ 32 elems
#define KS1(x) ((x) ^ 32)

  for (int kc = 0; kc < DN / BK; ++kc) {
    const int k = kc * BK;
    __syncthreads();   // previous chunk fully consumed
#pragma unroll
    for (int it = 0; it < 4; ++it) {
      const size_t g = (size_t)it * 32 * DN + k;
      unsigned short* l = ldsW + it * 32 * BK;
      gload_lds16(pAr + g, l + 0 * TILE);
      gload_lds16(pAf + g, l + 1 * TILE);
      gload_lds16(pBr + g, l + 2 * TILE);
      gload_lds16(pBf + g, l + 3 * TILE);
    }
    __syncthreads();   // vmcnt drained -> LDS valid

#pragma unroll
    for (int ksub = 0; ksub < 2; ++ksub) {
      bf16x8 ar[4], af[4], br[4], bf[4];
#pragma unroll
      for (int i = 0; i < 4; ++i) {
        const int oa = ksub ? KS1(ra[i]) : ra[i];
        const int ob = ksub ? KS1(rb[i]) : rb[i];
        ar[i] = *(const bf16x8*)(S + 0 * TILE + oa);
        af[i] = *(const bf16x8*)(S + 1 * TILE + oa);
        br[i] = *(const bf16x8*)(S + 2 * TILE + ob);
        bf[i] = *(const bf16x8*)(S + 3 * TILE + ob);
      }
#pragma unroll
      for (int i = 0; i < 4; ++i)
#pragma unroll
        for (int j = 0; j < 4; ++j) {
          acc[0][i][j] = __builtin_amdgcn_mfma_f32_16x16x32_bf16(ar[i], br[j], acc[0][i][j], 0, 0, 0);
          acc[1][i][j] = __builtin_amdgcn_mfma_f32_16x16x32_bf16(af[i], bf[j], acc[1][i][j], 0, 0, 0);
        }
    }
  }

  // epilogue: sq = ||t||^2 + ||c||^2 - 2*dot ; p = w_r*exp(-d_r) + w_f*exp(-d_f)
  const float* tn_r = norms;
  const float* tn_f = norms + QN;
  const float* cn_r = norms + 2 * QN;
  const float* cn_f = norms + 3 * QN;

#pragma unroll
  for (int i = 0; i < 4; ++i) {
#pragma unroll
    for (int r = 0; r < 4; ++r) {
      const int tq = row0 + wr * 64 + i * 16 + lq * 4 + r;   // C/D row = (lane>>4)*4 + reg
      const float tnr = tn_r[tq];
      const float tnf = tn_f[tq];
      const float cr = c_r[tq], cf = c_f[tq];
      const float inv = 1.f / (cr + cf);
      const float wgr = cr * inv, wgf = cf * inv;
#pragma unroll
      for (int j = 0; j < 4; ++j) {
        const int cc = col0 + wc * 64 + j * 16 + lr;          // C/D col = lane&15
        const float sr_ = tnr + cn_r[cc] - 2.f * acc[0][i][j][r];
        const float sf_ = tnf + cn_f[cc] - 2.f * acc[1][i][j][r];
        const float dr = sqrtf(fmaxf(sr_, 0.f));
        const float df = sqrtf(fmaxf(sf_, 0.f));
        const float p = wgr * __expf(-dr) + wgf * __expf(-df);
        out[(size_t)tq * CN + cc] = p;
      }
    }
  }
}

// Per-row sum + normalize, in place. Deterministic (no atomics).
__global__ void norm_kernel(float* __restrict__ out) {
  const int row = blockIdx.x;
  const int t = threadIdx.x;
  float4* p = (float4*)(out + (size_t)row * CN);
  float4 v[4];
  float s = 0.f;
#pragma unroll
  for (int i = 0; i < 4; ++i) {
    v[i] = p[t + 256 * i];
    s += v[i].x + v[i].y + v[i].z + v[i].w;
  }
#pragma unroll
  for (int o = 32; o > 0; o >>= 1) s += __shfl_down(s, o);
  __shared__ float red[4];
  if ((t & 63) == 0) red[t >> 6] = s;
  __syncthreads();
  const float inv = 1.f / (red[0] + red[1] + red[2] + red[3]);
#pragma unroll
  for (int i = 0; i < 4; ++i) {
    v[i].x *= inv; v[i].y *= inv; v[i].z *= inv; v[i].w *= inv;
    p[t + 256 * i] = v[i];
  }
}

extern "C" void kernel_launch(void* const* d_in, const int* in_sizes, int n_in,
                              void* d_out, int out_size, void* d_ws, size_t ws_size,
                              hipStream_t stream) {
  const float* ctx_r = (const float*)d_in[0];
  const float* ctx_f = (const float*)d_in[1];
  const float* tgt_r = (const float*)d_in[2];
  const float* tgt_f = (const float*)d_in[3];
  const float* c_r   = (const float*)d_in[4];
  const float* c_f   = (const float*)d_in[5];
  float* out = (float*)d_out;
  unsigned short* ws16 = (unsigned short*)d_ws;
  float* norms = (float*)(ws16 + 4 * MATSZ);

  prep_kernel<<<dim3(QN, 4), 256, 0, stream>>>(tgt_r, tgt_f, ctx_r, ctx_f, ws16, norms);
  gemm_kernel<<<dim3(CN / BN, QN / BM), 256, 0, stream>>>(ws16, norms, c_r, c_f, out);
  norm_kernel<<<QN, 256, 0, stream>>>(out);
}